// Round 1
// baseline (1068.273 us; speedup 1.0000x reference)
//
#include <hip/hip_runtime.h>
#include <math.h>

// GATv2 encoder, 3 layers, heads=1, C=64.
// Strategy:
//   - counting-sort edges by dst once per call (shared by all 3 layers)
//   - per layer: k_linear (xl=x@Wl+bl, xr=x@Wr+br, W staged in LDS)
//                k_edge   (one wave per dst node, lane=channel,
//                          online softmax, single gather of xl[src] per edge)

#define NEG_SLOPE 0.2f

// ---------------- counting sort ----------------

__global__ void k_count(const int* __restrict__ dst, int E, int* __restrict__ counts) {
    int e = blockIdx.x * blockDim.x + threadIdx.x;
    if (e < E) atomicAdd(&counts[dst[e]], 1);
}

// single-block exclusive scan over n counts -> offsets[n+1], cursor[n]
__global__ __launch_bounds__(1024) void k_scan(const int* __restrict__ counts, int n,
                                               int* __restrict__ offsets, int* __restrict__ cursor) {
    __shared__ int wsum[16];
    __shared__ int wpre[16];
    __shared__ int chunktot;
    int tid = threadIdx.x;
    int lane = tid & 63;
    int w = tid >> 6;
    int carry = 0;
    for (int base = 0; base < n; base += 1024) {
        int i = base + tid;
        int v = (i < n) ? counts[i] : 0;
        // wave inclusive scan
        int incl = v;
        #pragma unroll
        for (int off = 1; off < 64; off <<= 1) {
            int t = __shfl_up(incl, off, 64);
            if (lane >= off) incl += t;
        }
        if (lane == 63) wsum[w] = incl;
        __syncthreads();
        if (tid == 0) {
            int acc = 0;
            #pragma unroll
            for (int j = 0; j < 16; ++j) { int t = wsum[j]; wpre[j] = acc; acc += t; }
            chunktot = acc;
        }
        __syncthreads();
        int excl = incl - v + wpre[w] + carry;
        if (i < n) { offsets[i] = excl; cursor[i] = excl; }
        carry += chunktot;
        __syncthreads();  // protect wsum/chunktot before next chunk
    }
    if (tid == 0) offsets[n] = carry;
}

__global__ void k_scatter(const int* __restrict__ src, const int* __restrict__ dst,
                          const float* __restrict__ ea, int E,
                          int* __restrict__ cursor,
                          int* __restrict__ ssrc, float* __restrict__ sea) {
    int e = blockIdx.x * blockDim.x + threadIdx.x;
    if (e < E) {
        int d = dst[e];
        int pos = atomicAdd(&cursor[d], 1);
        ssrc[pos] = src[e];
        sea[pos]  = ea[e];
    }
}

// ---------------- linear: xl = x@Wl+bl, xr = x@Wr+br ----------------
// block=256 threads, 16 nodes per block, Wl/Wr + 16 x-rows staged in LDS.
template<int DIN>
__global__ __launch_bounds__(256) void k_linear(
    const float* __restrict__ x,
    const float* __restrict__ Wl, const float* __restrict__ bl,
    const float* __restrict__ Wr, const float* __restrict__ br,
    float* __restrict__ xl, float* __restrict__ xr, int n)
{
    __shared__ float sWl[DIN * 64];
    __shared__ float sWr[DIN * 64];
    __shared__ float sX[16 * DIN];
    int tid = threadIdx.x;
    for (int i = tid * 4; i < DIN * 64; i += 256 * 4) {
        *(float4*)&sWl[i] = *(const float4*)&Wl[i];
        *(float4*)&sWr[i] = *(const float4*)&Wr[i];
    }
    int nb = blockIdx.x * 16;
    int totx = n * DIN;
    for (int i = tid * 4; i < 16 * DIN; i += 256 * 4) {
        int g = nb * DIN + i;
        if (g < totx) *(float4*)&sX[i] = *(const float4*)&x[g];
    }
    __syncthreads();
    int lane = tid & 63;
    int grp = tid >> 6;
    float blv = bl[lane], brv = br[lane];
    for (int j = 0; j < 4; ++j) {
        int nl = grp * 4 + j;
        int node = nb + nl;
        if (node >= n) break;
        float accL = blv, accR = brv;
        #pragma unroll 8
        for (int k = 0; k < DIN; ++k) {
            float xk = sX[nl * DIN + k];
            accL += xk * sWl[k * 64 + lane];
            accR += xk * sWr[k * 64 + lane];
        }
        xl[node * 64 + lane] = accL;
        xr[node * 64 + lane] = accR;
    }
}

// ---------------- edge phase: one wave per dst node, online softmax ----------------
__global__ __launch_bounds__(256) void k_edge(
    const float* __restrict__ xl, const float* __restrict__ xr,
    const int* __restrict__ ssrc, const float* __restrict__ sea,
    const int* __restrict__ offsets,
    const float* __restrict__ We, const float* __restrict__ att,
    const float* __restrict__ b,
    float* __restrict__ out, int n, int relu)
{
    int wave = threadIdx.x >> 6;
    int lane = threadIdx.x & 63;
    int v = blockIdx.x * 4 + wave;
    if (v >= n) return;
    int start = offsets[v];
    int end   = offsets[v + 1];
    float xr_c  = xr[v * 64 + lane];
    float We_c  = We[lane];
    float att_c = att[lane];
    float M = -INFINITY, S = 0.f, O = 0.f;
    for (int e = start; e < end; ++e) {
        int s    = ssrc[e];          // uniform across wave -> broadcast
        float ea = sea[e];
        float xlc = xl[s * 64 + lane];   // coalesced 256B gather
        float m = xlc + xr_c + ea * We_c;
        m = m > 0.f ? m : NEG_SLOPE * m;
        float p = m * att_c;
        // butterfly all-reduce over 64 lanes
        #pragma unroll
        for (int off = 32; off; off >>= 1) p += __shfl_xor(p, off, 64);
        float newM = fmaxf(M, p);
        float scale = __expf(M - newM);   // exp(-inf)=0 handles first edge
        float wgt   = __expf(p - newM);
        S = S * scale + wgt;
        O = O * scale + wgt * xlc;
        M = newM;
    }
    float res = O / (S + 1e-16f) + b[lane];
    if (relu) res = fmaxf(res, 0.f);
    out[v * 64 + lane] = res;
}

// ---------------- launcher ----------------
extern "C" void kernel_launch(void* const* d_in, const int* in_sizes, int n_in,
                              void* d_out, int out_size, void* d_ws, size_t ws_size,
                              hipStream_t stream)
{
    const float* x  = (const float*)d_in[0];
    const int*   ei = (const int*)d_in[1];
    const float* ea = (const float*)d_in[2];
    const int N = in_sizes[0] / 128;
    const int E = in_sizes[1] / 2;
    const int* src = ei;
    const int* dst = ei + E;

    // layer params: Wl, bl, Wr, br, We, att, b  (7 per layer)
    const float* P[21];
    for (int i = 0; i < 21; ++i) P[i] = (const float*)d_in[3 + i];

    char* ws = (char*)d_ws;
    size_t off = 0;
    auto alloc = [&](size_t bytes) { char* p = ws + off; off += (bytes + 255) & ~255ULL; return p; };
    float* xl      = (float*)alloc((size_t)N * 64 * 4);
    float* xr      = (float*)alloc((size_t)N * 64 * 4);
    float* h0      = (float*)alloc((size_t)N * 64 * 4);
    float* h1      = (float*)alloc((size_t)N * 64 * 4);
    int*   ssrc    = (int*)alloc((size_t)E * 4);
    float* sea     = (float*)alloc((size_t)E * 4);
    int*   counts  = (int*)alloc((size_t)N * 4);
    int*   offsets = (int*)alloc((size_t)(N + 1) * 4);
    int*   cursor  = (int*)alloc((size_t)N * 4);

    // ---- sort edges by dst (shared across the 3 layers) ----
    hipMemsetAsync(counts, 0, (size_t)N * 4, stream);
    k_count<<<(E + 255) / 256, 256, 0, stream>>>(dst, E, counts);
    k_scan<<<1, 1024, 0, stream>>>(counts, N, offsets, cursor);
    k_scatter<<<(E + 255) / 256, 256, 0, stream>>>(src, dst, ea, E, cursor, ssrc, sea);

    const int lgrid = (N + 15) / 16;
    const int egrid = (N + 3) / 4;

    // layer 0 (din=128) -> h0, relu
    k_linear<128><<<lgrid, 256, 0, stream>>>(x, P[0], P[1], P[2], P[3], xl, xr, N);
    k_edge<<<egrid, 256, 0, stream>>>(xl, xr, ssrc, sea, offsets, P[4], P[5], P[6], h0, N, 1);
    // layer 1 (din=64) -> h1, relu
    k_linear<64><<<lgrid, 256, 0, stream>>>(h0, P[7], P[8], P[9], P[10], xl, xr, N);
    k_edge<<<egrid, 256, 0, stream>>>(xl, xr, ssrc, sea, offsets, P[11], P[12], P[13], h1, N, 1);
    // layer 2 (din=64) -> d_out, no relu
    k_linear<64><<<lgrid, 256, 0, stream>>>(h1, P[14], P[15], P[16], P[17], xl, xr, N);
    k_edge<<<egrid, 256, 0, stream>>>(xl, xr, ssrc, sea, offsets, P[18], P[19], P[20], (float*)d_out, N, 0);
}

// Round 7
// 766.327 us; speedup vs baseline: 1.3940x; 1.3940x over previous
//
#include <hip/hip_runtime.h>
#include <math.h>

// GATv2 encoder, 3 layers, heads=1, C=64.
//   - counting-sort edges by dst once per call (shared by all 3 layers)
//   - k_linear: xl=x@Wl+bl, xr=x@Wr+br, W in LDS, k-outer register blocking
//   - k_edge: one wave per dst node, lane=channel, online softmax,
//             8-edge batches to break the dependent latency chain

#define NEG_SLOPE 0.2f

// ---------------- counting sort ----------------

__global__ void k_count(const int* __restrict__ dst, int E, int* __restrict__ counts) {
    int e = blockIdx.x * blockDim.x + threadIdx.x;
    if (e < E) atomicAdd(&counts[dst[e]], 1);
}

// single-block exclusive scan over n counts -> offsets[n+1], cursor[n]
__global__ __launch_bounds__(1024) void k_scan(const int* __restrict__ counts, int n,
                                               int* __restrict__ offsets, int* __restrict__ cursor) {
    __shared__ int wsum[16];
    __shared__ int wpre[16];
    __shared__ int chunktot;
    int tid = threadIdx.x;
    int lane = tid & 63;
    int w = tid >> 6;
    int carry = 0;
    for (int base = 0; base < n; base += 1024) {
        int i = base + tid;
        int v = (i < n) ? counts[i] : 0;
        int incl = v;
        #pragma unroll
        for (int off = 1; off < 64; off <<= 1) {
            int t = __shfl_up(incl, off, 64);
            if (lane >= off) incl += t;
        }
        if (lane == 63) wsum[w] = incl;
        __syncthreads();
        if (tid == 0) {
            int acc = 0;
            #pragma unroll
            for (int j = 0; j < 16; ++j) { int t = wsum[j]; wpre[j] = acc; acc += t; }
            chunktot = acc;
        }
        __syncthreads();
        int excl = incl - v + wpre[w] + carry;
        if (i < n) { offsets[i] = excl; cursor[i] = excl; }
        carry += chunktot;
        __syncthreads();
    }
    if (tid == 0) offsets[n] = carry;
}

__global__ void k_scatter(const int* __restrict__ src, const int* __restrict__ dst,
                          const float* __restrict__ ea, int E,
                          int* __restrict__ cursor,
                          int* __restrict__ ssrc, float* __restrict__ sea) {
    int e = blockIdx.x * blockDim.x + threadIdx.x;
    if (e < E) {
        int d = dst[e];
        int pos = atomicAdd(&cursor[d], 1);
        ssrc[pos] = src[e];
        sea[pos]  = ea[e];
    }
}

// ---------------- linear: xl = x@Wl+bl, xr = x@Wr+br ----------------
// block=256 threads, 16 nodes/block. k-outer loop: each sWl/sWr element
// read once per wave and reused for 4 nodes (4x fewer LDS reads).
template<int DIN>
__global__ __launch_bounds__(256) void k_linear(
    const float* __restrict__ x,
    const float* __restrict__ Wl, const float* __restrict__ bl,
    const float* __restrict__ Wr, const float* __restrict__ br,
    float* __restrict__ xl, float* __restrict__ xr, int n)
{
    __shared__ float sWl[DIN * 64];
    __shared__ float sWr[DIN * 64];
    __shared__ float sX[16 * DIN];
    int tid = threadIdx.x;
    for (int i = tid * 4; i < DIN * 64; i += 256 * 4) {
        *(float4*)&sWl[i] = *(const float4*)&Wl[i];
        *(float4*)&sWr[i] = *(const float4*)&Wr[i];
    }
    int nb = blockIdx.x * 16;
    int totx = n * DIN;
    for (int i = tid * 4; i < 16 * DIN; i += 256 * 4) {
        int g = nb * DIN + i;
        if (g < totx) *(float4*)&sX[i] = *(const float4*)&x[g];
    }
    __syncthreads();
    int lane = tid & 63;
    int grp = tid >> 6;          // wave id: owns nodes grp*4 .. grp*4+3
    float blv = bl[lane], brv = br[lane];
    float accL[4], accR[4];
    #pragma unroll
    for (int j = 0; j < 4; ++j) { accL[j] = blv; accR[j] = brv; }
    const float* sx0 = &sX[(grp * 4) * DIN];
    #pragma unroll 4
    for (int k = 0; k < DIN; ++k) {
        float wl = sWl[k * 64 + lane];
        float wr = sWr[k * 64 + lane];
        #pragma unroll
        for (int j = 0; j < 4; ++j) {
            float xk = sx0[j * DIN + k];    // wave-broadcast LDS read
            accL[j] += xk * wl;
            accR[j] += xk * wr;
        }
    }
    #pragma unroll
    for (int j = 0; j < 4; ++j) {
        int node = nb + grp * 4 + j;
        if (node < n) {
            xl[node * 64 + lane] = accL[j];
            xr[node * 64 + lane] = accR[j];
        }
    }
}

// ---------------- edge phase: one wave per dst node, online softmax ----------------
// 8-edge batches: 8 independent gathers + 8 independent shuffle-reduce chains
// per step + one rescale per batch -> ~5x shorter dependent chain per edge.
__global__ __launch_bounds__(256) void k_edge(
    const float* __restrict__ xl, const float* __restrict__ xr,
    const int* __restrict__ ssrc, const float* __restrict__ sea,
    const int* __restrict__ offsets,
    const float* __restrict__ We, const float* __restrict__ att,
    const float* __restrict__ b,
    float* __restrict__ out, int n, int relu)
{
    int wave = threadIdx.x >> 6;
    int lane = threadIdx.x & 63;
    int v = blockIdx.x * 4 + wave;
    if (v >= n) return;
    int start = offsets[v];
    int end   = offsets[v + 1];
    float xr_c  = xr[v * 64 + lane];
    float We_c  = We[lane];
    float att_c = att[lane];
    float M = -INFINITY, S = 0.f, O = 0.f;

    int e = start;
    for (; e + 8 <= end; e += 8) {
        int   s[8]; float eav[8], xlc[8], p[8];
        #pragma unroll
        for (int i = 0; i < 8; ++i) { s[i] = ssrc[e + i]; eav[i] = sea[e + i]; }
        #pragma unroll
        for (int i = 0; i < 8; ++i) xlc[i] = xl[s[i] * 64 + lane];  // 8 overlapped gathers
        #pragma unroll
        for (int i = 0; i < 8; ++i) {
            float m = xlc[i] + xr_c + eav[i] * We_c;
            m = m > 0.f ? m : NEG_SLOPE * m;
            p[i] = m * att_c;
        }
        #pragma unroll
        for (int off = 32; off; off >>= 1) {
            #pragma unroll
            for (int i = 0; i < 8; ++i) p[i] += __shfl_xor(p[i], off, 64);
        }
        float bm = fmaxf(fmaxf(fmaxf(p[0], p[1]), fmaxf(p[2], p[3])),
                         fmaxf(fmaxf(p[4], p[5]), fmaxf(p[6], p[7])));
        float newM = fmaxf(M, bm);
        float scale = __expf(M - newM);     // exp(-inf)=0 handles first batch
        float w[8];
        #pragma unroll
        for (int i = 0; i < 8; ++i) w[i] = __expf(p[i] - newM);
        float sw = ((w[0] + w[1]) + (w[2] + w[3])) + ((w[4] + w[5]) + (w[6] + w[7]));
        float ow = 0.f;
        #pragma unroll
        for (int i = 0; i < 8; ++i) ow += w[i] * xlc[i];
        S = S * scale + sw;
        O = O * scale + ow;
        M = newM;
    }
    for (; e < end; ++e) {                  // remainder (<8 edges)
        int s    = ssrc[e];
        float ea = sea[e];
        float xlc = xl[s * 64 + lane];
        float m = xlc + xr_c + ea * We_c;
        m = m > 0.f ? m : NEG_SLOPE * m;
        float p = m * att_c;
        #pragma unroll
        for (int off = 32; off; off >>= 1) p += __shfl_xor(p, off, 64);
        float newM = fmaxf(M, p);
        float scale = __expf(M - newM);
        float wgt   = __expf(p - newM);
        S = S * scale + wgt;
        O = O * scale + wgt * xlc;
        M = newM;
    }
    float res = O / (S + 1e-16f) + b[lane];
    if (relu) res = fmaxf(res, 0.f);
    out[v * 64 + lane] = res;
}

// ---------------- launcher ----------------
extern "C" void kernel_launch(void* const* d_in, const int* in_sizes, int n_in,
                              void* d_out, int out_size, void* d_ws, size_t ws_size,
                              hipStream_t stream)
{
    const float* x  = (const float*)d_in[0];
    const int*   ei = (const int*)d_in[1];
    const float* ea = (const float*)d_in[2];
    const int N = in_sizes[0] / 128;
    const int E = in_sizes[1] / 2;
    const int* src = ei;
    const int* dst = ei + E;

    const float* P[21];
    for (int i = 0; i < 21; ++i) P[i] = (const float*)d_in[3 + i];

    char* ws = (char*)d_ws;
    size_t off = 0;
    auto alloc = [&](size_t bytes) { char* p = ws + off; off += (bytes + 255) & ~255ULL; return p; };
    float* xl      = (float*)alloc((size_t)N * 64 * 4);
    float* xr      = (float*)alloc((size_t)N * 64 * 4);
    float* h0      = (float*)alloc((size_t)N * 64 * 4);
    float* h1      = (float*)alloc((size_t)N * 64 * 4);
    int*   ssrc    = (int*)alloc((size_t)E * 4);
    float* sea     = (float*)alloc((size_t)E * 4);
    int*   counts  = (int*)alloc((size_t)N * 4);
    int*   offsets = (int*)alloc((size_t)(N + 1) * 4);
    int*   cursor  = (int*)alloc((size_t)N * 4);

    hipMemsetAsync(counts, 0, (size_t)N * 4, stream);
    k_count<<<(E + 255) / 256, 256, 0, stream>>>(dst, E, counts);
    k_scan<<<1, 1024, 0, stream>>>(counts, N, offsets, cursor);
    k_scatter<<<(E + 255) / 256, 256, 0, stream>>>(src, dst, ea, E, cursor, ssrc, sea);

    const int lgrid = (N + 15) / 16;
    const int egrid = (N + 3) / 4;

    k_linear<128><<<lgrid, 256, 0, stream>>>(x, P[0], P[1], P[2], P[3], xl, xr, N);
    k_edge<<<egrid, 256, 0, stream>>>(xl, xr, ssrc, sea, offsets, P[4], P[5], P[6], h0, N, 1);
    k_linear<64><<<lgrid, 256, 0, stream>>>(h0, P[7], P[8], P[9], P[10], xl, xr, N);
    k_edge<<<egrid, 256, 0, stream>>>(xl, xr, ssrc, sea, offsets, P[11], P[12], P[13], h1, N, 1);
    k_linear<64><<<lgrid, 256, 0, stream>>>(h1, P[14], P[15], P[16], P[17], xl, xr, N);
    k_edge<<<egrid, 256, 0, stream>>>(xl, xr, ssrc, sea, offsets, P[18], P[19], P[20], (float*)d_out, N, 0);
}

// Round 8
// 751.013 us; speedup vs baseline: 1.4224x; 1.0204x over previous
//
#include <hip/hip_runtime.h>
#include <math.h>

// GATv2 encoder, 3 layers, heads=1, C=64.
//   - counting-sort edges by dst once per call (shared by all 3 layers)
//   - edge payload packed as int2{src, bits(ea)}: ONE 8B scattered write per
//     edge in k_scatter (R7 counters: 2x4B writes -> 145MB WRITE_SIZE, 11x
//     amplification, latency-bound), and ONE dwordx2 load per edge in k_edge.
//   - k_linear: xl=x@Wl+bl, xr=x@Wr+br, W in LDS, k-outer register blocking
//   - k_edge: one wave per dst node, lane=channel, online softmax,
//             8-edge batches to break the dependent latency chain

#define NEG_SLOPE 0.2f

// ---------------- counting sort ----------------

__global__ void k_count(const int* __restrict__ dst, int E, int* __restrict__ counts) {
    int e = blockIdx.x * blockDim.x + threadIdx.x;
    if (e < E) atomicAdd(&counts[dst[e]], 1);
}

// single-block exclusive scan over n counts -> offsets[n+1], cursor[n]
__global__ __launch_bounds__(1024) void k_scan(const int* __restrict__ counts, int n,
                                               int* __restrict__ offsets, int* __restrict__ cursor) {
    __shared__ int wsum[16];
    __shared__ int wpre[16];
    __shared__ int chunktot;
    int tid = threadIdx.x;
    int lane = tid & 63;
    int w = tid >> 6;
    int carry = 0;
    for (int base = 0; base < n; base += 1024) {
        int i = base + tid;
        int v = (i < n) ? counts[i] : 0;
        int incl = v;
        #pragma unroll
        for (int off = 1; off < 64; off <<= 1) {
            int t = __shfl_up(incl, off, 64);
            if (lane >= off) incl += t;
        }
        if (lane == 63) wsum[w] = incl;
        __syncthreads();
        if (tid == 0) {
            int acc = 0;
            #pragma unroll
            for (int j = 0; j < 16; ++j) { int t = wsum[j]; wpre[j] = acc; acc += t; }
            chunktot = acc;
        }
        __syncthreads();
        int excl = incl - v + wpre[w] + carry;
        if (i < n) { offsets[i] = excl; cursor[i] = excl; }
        carry += chunktot;
        __syncthreads();
    }
    if (tid == 0) offsets[n] = carry;
}

__global__ void k_scatter(const int* __restrict__ src, const int* __restrict__ dst,
                          const float* __restrict__ ea, int E,
                          int* __restrict__ cursor,
                          int2* __restrict__ srec) {
    int e = blockIdx.x * blockDim.x + threadIdx.x;
    if (e < E) {
        int d = dst[e];
        int pos = atomicAdd(&cursor[d], 1);
        srec[pos] = make_int2(src[e], __float_as_int(ea[e]));  // one 8B line touch
    }
}

// ---------------- linear: xl = x@Wl+bl, xr = x@Wr+br ----------------
// block=256 threads, 16 nodes/block. k-outer loop: each sWl/sWr element
// read once per wave and reused for 4 nodes (4x fewer LDS reads).
template<int DIN>
__global__ __launch_bounds__(256) void k_linear(
    const float* __restrict__ x,
    const float* __restrict__ Wl, const float* __restrict__ bl,
    const float* __restrict__ Wr, const float* __restrict__ br,
    float* __restrict__ xl, float* __restrict__ xr, int n)
{
    __shared__ float sWl[DIN * 64];
    __shared__ float sWr[DIN * 64];
    __shared__ float sX[16 * DIN];
    int tid = threadIdx.x;
    for (int i = tid * 4; i < DIN * 64; i += 256 * 4) {
        *(float4*)&sWl[i] = *(const float4*)&Wl[i];
        *(float4*)&sWr[i] = *(const float4*)&Wr[i];
    }
    int nb = blockIdx.x * 16;
    int totx = n * DIN;
    for (int i = tid * 4; i < 16 * DIN; i += 256 * 4) {
        int g = nb * DIN + i;
        if (g < totx) *(float4*)&sX[i] = *(const float4*)&x[g];
    }
    __syncthreads();
    int lane = tid & 63;
    int grp = tid >> 6;          // wave id: owns nodes grp*4 .. grp*4+3
    float blv = bl[lane], brv = br[lane];
    float accL[4], accR[4];
    #pragma unroll
    for (int j = 0; j < 4; ++j) { accL[j] = blv; accR[j] = brv; }
    const float* sx0 = &sX[(grp * 4) * DIN];
    #pragma unroll 4
    for (int k = 0; k < DIN; ++k) {
        float wl = sWl[k * 64 + lane];
        float wr = sWr[k * 64 + lane];
        #pragma unroll
        for (int j = 0; j < 4; ++j) {
            float xk = sx0[j * DIN + k];    // wave-broadcast LDS read
            accL[j] += xk * wl;
            accR[j] += xk * wr;
        }
    }
    #pragma unroll
    for (int j = 0; j < 4; ++j) {
        int node = nb + grp * 4 + j;
        if (node < n) {
            xl[node * 64 + lane] = accL[j];
            xr[node * 64 + lane] = accR[j];
        }
    }
}

// ---------------- edge phase: one wave per dst node, online softmax ----------------
// 8-edge batches: 8 independent gathers + 8 independent shuffle-reduce chains
// per step + one rescale per batch -> ~5x shorter dependent chain per edge.
__global__ __launch_bounds__(256) void k_edge(
    const float* __restrict__ xl, const float* __restrict__ xr,
    const int2* __restrict__ srec,
    const int* __restrict__ offsets,
    const float* __restrict__ We, const float* __restrict__ att,
    const float* __restrict__ b,
    float* __restrict__ out, int n, int relu)
{
    int wave = threadIdx.x >> 6;
    int lane = threadIdx.x & 63;
    int v = blockIdx.x * 4 + wave;
    if (v >= n) return;
    int start = offsets[v];
    int end   = offsets[v + 1];
    float xr_c  = xr[v * 64 + lane];
    float We_c  = We[lane];
    float att_c = att[lane];
    float M = -INFINITY, S = 0.f, O = 0.f;

    int e = start;
    for (; e + 8 <= end; e += 8) {
        int2 rec[8]; float xlc[8], p[8];
        #pragma unroll
        for (int i = 0; i < 8; ++i) rec[i] = srec[e + i];           // 8B dwordx2 each
        #pragma unroll
        for (int i = 0; i < 8; ++i) xlc[i] = xl[rec[i].x * 64 + lane];  // 8 overlapped gathers
        #pragma unroll
        for (int i = 0; i < 8; ++i) {
            float m = xlc[i] + xr_c + __int_as_float(rec[i].y) * We_c;
            m = m > 0.f ? m : NEG_SLOPE * m;
            p[i] = m * att_c;
        }
        #pragma unroll
        for (int off = 32; off; off >>= 1) {
            #pragma unroll
            for (int i = 0; i < 8; ++i) p[i] += __shfl_xor(p[i], off, 64);
        }
        float bm = fmaxf(fmaxf(fmaxf(p[0], p[1]), fmaxf(p[2], p[3])),
                         fmaxf(fmaxf(p[4], p[5]), fmaxf(p[6], p[7])));
        float newM = fmaxf(M, bm);
        float scale = __expf(M - newM);     // exp(-inf)=0 handles first batch
        float w[8];
        #pragma unroll
        for (int i = 0; i < 8; ++i) w[i] = __expf(p[i] - newM);
        float sw = ((w[0] + w[1]) + (w[2] + w[3])) + ((w[4] + w[5]) + (w[6] + w[7]));
        float ow = 0.f;
        #pragma unroll
        for (int i = 0; i < 8; ++i) ow += w[i] * xlc[i];
        S = S * scale + sw;
        O = O * scale + ow;
        M = newM;
    }
    for (; e < end; ++e) {                  // remainder (<8 edges)
        int2 rec = srec[e];
        float xlc = xl[rec.x * 64 + lane];
        float m = xlc + xr_c + __int_as_float(rec.y) * We_c;
        m = m > 0.f ? m : NEG_SLOPE * m;
        float p = m * att_c;
        #pragma unroll
        for (int off = 32; off; off >>= 1) p += __shfl_xor(p, off, 64);
        float newM = fmaxf(M, p);
        float scale = __expf(M - newM);
        float wgt   = __expf(p - newM);
        S = S * scale + wgt;
        O = O * scale + wgt * xlc;
        M = newM;
    }
    float res = O / (S + 1e-16f) + b[lane];
    if (relu) res = fmaxf(res, 0.f);
    out[v * 64 + lane] = res;
}

// ---------------- launcher ----------------
extern "C" void kernel_launch(void* const* d_in, const int* in_sizes, int n_in,
                              void* d_out, int out_size, void* d_ws, size_t ws_size,
                              hipStream_t stream)
{
    const float* x  = (const float*)d_in[0];
    const int*   ei = (const int*)d_in[1];
    const float* ea = (const float*)d_in[2];
    const int N = in_sizes[0] / 128;
    const int E = in_sizes[1] / 2;
    const int* src = ei;
    const int* dst = ei + E;

    const float* P[21];
    for (int i = 0; i < 21; ++i) P[i] = (const float*)d_in[3 + i];

    char* ws = (char*)d_ws;
    size_t off = 0;
    auto alloc = [&](size_t bytes) { char* p = ws + off; off += (bytes + 255) & ~255ULL; return p; };
    float* xl      = (float*)alloc((size_t)N * 64 * 4);
    float* xr      = (float*)alloc((size_t)N * 64 * 4);
    float* h0      = (float*)alloc((size_t)N * 64 * 4);
    float* h1      = (float*)alloc((size_t)N * 64 * 4);
    int2*  srec    = (int2*)alloc((size_t)E * 8);
    int*   counts  = (int*)alloc((size_t)N * 4);
    int*   offsets = (int*)alloc((size_t)(N + 1) * 4);
    int*   cursor  = (int*)alloc((size_t)N * 4);

    hipMemsetAsync(counts, 0, (size_t)N * 4, stream);
    k_count<<<(E + 255) / 256, 256, 0, stream>>>(dst, E, counts);
    k_scan<<<1, 1024, 0, stream>>>(counts, N, offsets, cursor);
    k_scatter<<<(E + 255) / 256, 256, 0, stream>>>(src, dst, ea, E, cursor, srec);

    const int lgrid = (N + 15) / 16;
    const int egrid = (N + 3) / 4;

    k_linear<128><<<lgrid, 256, 0, stream>>>(x, P[0], P[1], P[2], P[3], xl, xr, N);
    k_edge<<<egrid, 256, 0, stream>>>(xl, xr, srec, offsets, P[4], P[5], P[6], h0, N, 1);
    k_linear<64><<<lgrid, 256, 0, stream>>>(h0, P[7], P[8], P[9], P[10], xl, xr, N);
    k_edge<<<egrid, 256, 0, stream>>>(xl, xr, srec, offsets, P[11], P[12], P[13], h1, N, 1);
    k_linear<64><<<lgrid, 256, 0, stream>>>(h1, P[14], P[15], P[16], P[17], xl, xr, N);
    k_edge<<<egrid, 256, 0, stream>>>(xl, xr, srec, offsets, P[18], P[19], P[20], (float*)d_out, N, 0);
}

// Round 13
// 669.941 us; speedup vs baseline: 1.5946x; 1.1210x over previous
//
#include <hip/hip_runtime.h>
#include <math.h>

// GATv2 encoder, 3 layers, heads=1, C=64.
//   - counting-sort edges by dst once per call (shared by all 3 layers)
//   - edge payload packed as int2{src, bits(ea)}
//   - k_linear: xl=x@Wl+bl, xr=x@Wr+br, W in LDS, k-outer register blocking
//   - k_edge: one wave per dst node, lane=channel, online softmax.
//     R8 rewrite: 8-edge multireduce (17 shuffles vs 48), 1 exp/lane vs 8,
//     masked padded tail (no serial remainder loop).

#define NEG_SLOPE 0.2f

// ---------------- counting sort ----------------

__global__ void k_count(const int* __restrict__ dst, int E, int* __restrict__ counts) {
    int e = blockIdx.x * blockDim.x + threadIdx.x;
    if (e < E) atomicAdd(&counts[dst[e]], 1);
}

// single-block exclusive scan over n counts -> offsets[n+1], cursor[n]
__global__ __launch_bounds__(1024) void k_scan(const int* __restrict__ counts, int n,
                                               int* __restrict__ offsets, int* __restrict__ cursor) {
    __shared__ int wsum[16];
    __shared__ int wpre[16];
    __shared__ int chunktot;
    int tid = threadIdx.x;
    int lane = tid & 63;
    int w = tid >> 6;
    int carry = 0;
    for (int base = 0; base < n; base += 1024) {
        int i = base + tid;
        int v = (i < n) ? counts[i] : 0;
        int incl = v;
        #pragma unroll
        for (int off = 1; off < 64; off <<= 1) {
            int t = __shfl_up(incl, off, 64);
            if (lane >= off) incl += t;
        }
        if (lane == 63) wsum[w] = incl;
        __syncthreads();
        if (tid == 0) {
            int acc = 0;
            #pragma unroll
            for (int j = 0; j < 16; ++j) { int t = wsum[j]; wpre[j] = acc; acc += t; }
            chunktot = acc;
        }
        __syncthreads();
        int excl = incl - v + wpre[w] + carry;
        if (i < n) { offsets[i] = excl; cursor[i] = excl; }
        carry += chunktot;
        __syncthreads();
    }
    if (tid == 0) offsets[n] = carry;
}

__global__ void k_scatter(const int* __restrict__ src, const int* __restrict__ dst,
                          const float* __restrict__ ea, int E,
                          int* __restrict__ cursor,
                          int2* __restrict__ srec) {
    int e = blockIdx.x * blockDim.x + threadIdx.x;
    if (e < E) {
        int d = dst[e];
        int pos = atomicAdd(&cursor[d], 1);
        srec[pos] = make_int2(src[e], __float_as_int(ea[e]));  // one 8B line touch
    }
}

// ---------------- linear: xl = x@Wl+bl, xr = x@Wr+br ----------------
template<int DIN>
__global__ __launch_bounds__(256) void k_linear(
    const float* __restrict__ x,
    const float* __restrict__ Wl, const float* __restrict__ bl,
    const float* __restrict__ Wr, const float* __restrict__ br,
    float* __restrict__ xl, float* __restrict__ xr, int n)
{
    __shared__ float sWl[DIN * 64];
    __shared__ float sWr[DIN * 64];
    __shared__ float sX[16 * DIN];
    int tid = threadIdx.x;
    for (int i = tid * 4; i < DIN * 64; i += 256 * 4) {
        *(float4*)&sWl[i] = *(const float4*)&Wl[i];
        *(float4*)&sWr[i] = *(const float4*)&Wr[i];
    }
    int nb = blockIdx.x * 16;
    int totx = n * DIN;
    for (int i = tid * 4; i < 16 * DIN; i += 256 * 4) {
        int g = nb * DIN + i;
        if (g < totx) *(float4*)&sX[i] = *(const float4*)&x[g];
    }
    __syncthreads();
    int lane = tid & 63;
    int grp = tid >> 6;          // wave id: owns nodes grp*4 .. grp*4+3
    float blv = bl[lane], brv = br[lane];
    float accL[4], accR[4];
    #pragma unroll
    for (int j = 0; j < 4; ++j) { accL[j] = blv; accR[j] = brv; }
    const float* sx0 = &sX[(grp * 4) * DIN];
    #pragma unroll 4
    for (int k = 0; k < DIN; ++k) {
        float wl = sWl[k * 64 + lane];
        float wr = sWr[k * 64 + lane];
        #pragma unroll
        for (int j = 0; j < 4; ++j) {
            float xk = sx0[j * DIN + k];    // wave-broadcast LDS read
            accL[j] += xk * wl;
            accR[j] += xk * wr;
        }
    }
    #pragma unroll
    for (int j = 0; j < 4; ++j) {
        int node = nb + grp * 4 + j;
        if (node < n) {
            xl[node * 64 + lane] = accL[j];
            xr[node * 64 + lane] = accR[j];
        }
    }
}

// ---------------- edge phase ----------------
// One wave per dst node, lane=channel. All edges in padded 8-batches.
// Multireduce: 8 dot-products reduced with 17 shuffles; lane l ends with
// edge (l&7)'s full logit. One exp/lane; per-edge weights re-broadcast via
// constant-source shuffles (static register indexing).
__global__ __launch_bounds__(256) void k_edge(
    const float* __restrict__ xl, const float* __restrict__ xr,
    const int2* __restrict__ srec,
    const int* __restrict__ offsets,
    const float* __restrict__ We, const float* __restrict__ att,
    const float* __restrict__ b,
    float* __restrict__ out, int n, int relu)
{
    int wave = threadIdx.x >> 6;
    int lane = threadIdx.x & 63;
    int v = blockIdx.x * 4 + wave;
    if (v >= n) return;
    int start = offsets[v];
    int end   = offsets[v + 1];
    float xr_c  = xr[v * 64 + lane];
    float We_c  = We[lane];
    float att_c = att[lane];
    float M = -INFINITY, S = 0.f, O = 0.f;

    for (int e = start; e < end; e += 8) {
        int cnt = end - e;                  // >= 1; pad slots i >= cnt
        int2 rec[8]; float xlc[8], p[8];
        #pragma unroll
        for (int i = 0; i < 8; ++i) {
            int ii = (i < cnt) ? i : 0;     // clamp padded loads to a valid edge
            rec[i] = srec[e + ii];
        }
        #pragma unroll
        for (int i = 0; i < 8; ++i) xlc[i] = xl[rec[i].x * 64 + lane];  // coalesced gathers
        #pragma unroll
        for (int i = 0; i < 8; ++i) {
            float m = xlc[i] + xr_c + __int_as_float(rec[i].y) * We_c;
            m = m > 0.f ? m : NEG_SLOPE * m;
            p[i] = (i < cnt) ? m * att_c : -INFINITY;   // padded -> weight 0
        }
        // multireduce: 8 vectors -> 1; lane l holds edge (l&7)'s full sum
        float q[4];
        #pragma unroll
        for (int i = 0; i < 4; ++i) {
            float a = p[2*i]   + __shfl_xor(p[2*i],   1, 64);
            float c = p[2*i+1] + __shfl_xor(p[2*i+1], 1, 64);
            q[i] = (lane & 1) ? c : a;
        }
        float r[2];
        #pragma unroll
        for (int i = 0; i < 2; ++i) {
            float a = q[2*i]   + __shfl_xor(q[2*i],   2, 64);
            float c = q[2*i+1] + __shfl_xor(q[2*i+1], 2, 64);
            r[i] = (lane & 2) ? c : a;
        }
        float s_;
        {
            float a = r[0] + __shfl_xor(r[0], 4, 64);
            float c = r[1] + __shfl_xor(r[1], 4, 64);
            s_ = (lane & 4) ? c : a;
        }
        s_ += __shfl_xor(s_, 8, 64);
        s_ += __shfl_xor(s_, 16, 64);
        s_ += __shfl_xor(s_, 32, 64);       // replicated across 8-groups

        // max over the 8 edge slots (replication makes this global)
        float bm = s_;
        bm = fmaxf(bm, __shfl_xor(bm, 1, 64));
        bm = fmaxf(bm, __shfl_xor(bm, 2, 64));
        bm = fmaxf(bm, __shfl_xor(bm, 4, 64));

        float newM = fmaxf(M, bm);
        float scale = __expf(M - newM);     // exp(-inf)=0 on first batch
        float wv = __expf(s_ - newM);       // ONE exp: this lane's edge weight

        // per-edge weights, constant-source broadcast (lanes 0..7 hold them)
        float w0 = __shfl(wv, 0, 64), w1 = __shfl(wv, 1, 64);
        float w2 = __shfl(wv, 2, 64), w3 = __shfl(wv, 3, 64);
        float w4 = __shfl(wv, 4, 64), w5 = __shfl(wv, 5, 64);
        float w6 = __shfl(wv, 6, 64), w7 = __shfl(wv, 7, 64);
        float sw = ((w0 + w1) + (w2 + w3)) + ((w4 + w5) + (w6 + w7));
        float ow = w0*xlc[0] + w1*xlc[1] + w2*xlc[2] + w3*xlc[3]
                 + w4*xlc[4] + w5*xlc[5] + w6*xlc[6] + w7*xlc[7];
        S = S * scale + sw;
        O = O * scale + ow;
        M = newM;
    }
    float res = O / (S + 1e-16f) + b[lane];
    if (relu) res = fmaxf(res, 0.f);
    out[v * 64 + lane] = res;
}

// ---------------- launcher ----------------
extern "C" void kernel_launch(void* const* d_in, const int* in_sizes, int n_in,
                              void* d_out, int out_size, void* d_ws, size_t ws_size,
                              hipStream_t stream)
{
    const float* x  = (const float*)d_in[0];
    const int*   ei = (const int*)d_in[1];
    const float* ea = (const float*)d_in[2];
    const int N = in_sizes[0] / 128;
    const int E = in_sizes[1] / 2;
    const int* src = ei;
    const int* dst = ei + E;

    const float* P[21];
    for (int i = 0; i < 21; ++i) P[i] = (const float*)d_in[3 + i];

    char* ws = (char*)d_ws;
    size_t off = 0;
    auto alloc = [&](size_t bytes) { char* p = ws + off; off += (bytes + 255) & ~255ULL; return p; };
    float* xl      = (float*)alloc((size_t)N * 64 * 4);
    float* xr      = (float*)alloc((size_t)N * 64 * 4);
    float* h0      = (float*)alloc((size_t)N * 64 * 4);
    float* h1      = (float*)alloc((size_t)N * 64 * 4);
    int2*  srec    = (int2*)alloc((size_t)E * 8);
    int*   counts  = (int*)alloc((size_t)N * 4);
    int*   offsets = (int*)alloc((size_t)(N + 1) * 4);
    int*   cursor  = (int*)alloc((size_t)N * 4);

    hipMemsetAsync(counts, 0, (size_t)N * 4, stream);
    k_count<<<(E + 255) / 256, 256, 0, stream>>>(dst, E, counts);
    k_scan<<<1, 1024, 0, stream>>>(counts, N, offsets, cursor);
    k_scatter<<<(E + 255) / 256, 256, 0, stream>>>(src, dst, ea, E, cursor, srec);

    const int lgrid = (N + 15) / 16;
    const int egrid = (N + 3) / 4;

    k_linear<128><<<lgrid, 256, 0, stream>>>(x, P[0], P[1], P[2], P[3], xl, xr, N);
    k_edge<<<egrid, 256, 0, stream>>>(xl, xr, srec, offsets, P[4], P[5], P[6], h0, N, 1);
    k_linear<64><<<lgrid, 256, 0, stream>>>(h0, P[7], P[8], P[9], P[10], xl, xr, N);
    k_edge<<<egrid, 256, 0, stream>>>(xl, xr, srec, offsets, P[11], P[12], P[13], h1, N, 1);
    k_linear<64><<<lgrid, 256, 0, stream>>>(h1, P[14], P[15], P[16], P[17], xl, xr, N);
    k_edge<<<egrid, 256, 0, stream>>>(xl, xr, srec, offsets, P[18], P[19], P[20], (float*)d_out, N, 0);
}

// Round 14
// 542.557 us; speedup vs baseline: 1.9690x; 1.2348x over previous
//
#include <hip/hip_runtime.h>
#include <math.h>

// GATv2 encoder, 3 layers, heads=1, C=64.
// Sort-by-dst subsystem (R13 rewrite): atomic-free two-level bucket sort.
//   R13 counters: old k_scatter 111us, WRITE_SIZE 101MB for 12.8MB payload
//   (1.6M random 8B writes x 64B lines), VALUBusy 0.4% -> random-line-touch
//   bound. Fix: bucket edges (dst>>8, 196 buckets) with per-(bucket,block)
//   cursors precomputed by scan (NO global atomics); writes land in ~32-edge
//   contiguous runs (kA) / 64KB L2-resident windows (kB) so lines merge.
//   kB emits final srec{src,ea} + per-node CSR offsets directly.
// k_linear / k_edge byte-identical to R13 (multireduce edge kernel).

#define NEG_SLOPE 0.2f

// ---------------- pass A: per-(bucket,block) histogram ----------------
__global__ __launch_bounds__(256) void kA_hist(
    const int* __restrict__ dst, int E, int nbuck, int chunk,
    int* __restrict__ blockhist /* [nbuck][nblk] */)
{
    __shared__ int h[256];
    int tid = threadIdx.x, blk = blockIdx.x, nblk = gridDim.x;
    for (int i = tid; i < nbuck; i += 256) h[i] = 0;
    __syncthreads();
    int s0 = blk * chunk, s1 = min(s0 + chunk, E);
    for (int e = s0 + tid; e < s1; e += 256)
        atomicAdd(&h[dst[e] >> 8], 1);
    __syncthreads();
    for (int i = tid; i < nbuck; i += 256)
        blockhist[i * nblk + blk] = h[i];
}

// single-block exclusive scan over n counts -> offsets[n+1]
__global__ __launch_bounds__(1024) void k_scan(const int* __restrict__ counts, int n,
                                               int* __restrict__ offsets) {
    __shared__ int wsum[16];
    __shared__ int wpre[16];
    __shared__ int chunktot;
    int tid = threadIdx.x;
    int lane = tid & 63;
    int w = tid >> 6;
    int carry = 0;
    for (int base = 0; base < n; base += 1024) {
        int i = base + tid;
        int v = (i < n) ? counts[i] : 0;
        int incl = v;
        #pragma unroll
        for (int off = 1; off < 64; off <<= 1) {
            int t = __shfl_up(incl, off, 64);
            if (lane >= off) incl += t;
        }
        if (lane == 63) wsum[w] = incl;
        __syncthreads();
        if (tid == 0) {
            int acc = 0;
            #pragma unroll
            for (int j = 0; j < 16; ++j) { int t = wsum[j]; wpre[j] = acc; acc += t; }
            chunktot = acc;
        }
        __syncthreads();
        int excl = incl - v + wpre[w] + carry;
        if (i < n) offsets[i] = excl;
        carry += chunktot;
        __syncthreads();
    }
    if (tid == 0) offsets[n] = carry;
}

// ---------------- pass A scatter: edges -> bucket-grouped tmp ----------------
// Atomic-free globally: block's cursor per bucket precomputed by the scan.
// Record: {x = (dst<<16)|src (both < 65536), y = bits(ea)}.
__global__ __launch_bounds__(256) void kA_scatter(
    const int* __restrict__ src, const int* __restrict__ dst,
    const float* __restrict__ ea, int E, int nbuck, int chunk, int nblk,
    const int* __restrict__ cursA, int2* __restrict__ tmp)
{
    __shared__ int cur[256];
    int tid = threadIdx.x, blk = blockIdx.x;
    for (int i = tid; i < nbuck; i += 256) cur[i] = cursA[i * nblk + blk];
    __syncthreads();
    int s0 = blk * chunk, s1 = min(s0 + chunk, E);
    for (int e = s0 + tid; e < s1; e += 256) {
        int d = dst[e];
        int pos = atomicAdd(&cur[d >> 8], 1);        // LDS atomic only
        tmp[pos] = make_int2((d << 16) | src[e], __float_as_int(ea[e]));
    }
}

// ---------------- pass B: within-bucket counting sort + CSR offsets ----------
// One block per bucket (256 dst nodes, ~8k edges). Two coalesced reads of the
// bucket; writes confined to the bucket's 64KB output window (L2 merges).
__global__ __launch_bounds__(256) void kB_sort(
    const int2* __restrict__ tmp, const int* __restrict__ cursA,
    int nblk, int E, int n,
    int2* __restrict__ srec, int* __restrict__ offsets)
{
    __shared__ int h[256];
    __shared__ int cur2[256];
    int b = blockIdx.x, tid = threadIdx.x;
    int start = cursA[b * nblk];
    int end   = cursA[(b + 1) * nblk];
    h[tid] = 0;
    __syncthreads();
    for (int e = start + tid; e < end; e += 256)
        atomicAdd(&h[(tmp[e].x >> 16) & 255], 1);
    __syncthreads();
    if (tid == 0) {
        int acc = start;
        for (int i = 0; i < 256; ++i) { int c = h[i]; cur2[i] = acc; acc += c; }
    }
    __syncthreads();
    int v = (b << 8) + tid;
    if (v < n) offsets[v] = cur2[tid];
    if (b == 0 && tid == 0) offsets[n] = E;
    __syncthreads();
    for (int e = start + tid; e < end; e += 256) {
        int2 r = tmp[e];
        int pos = atomicAdd(&cur2[(r.x >> 16) & 255], 1);   // LDS atomic only
        srec[pos] = make_int2(r.x & 0xFFFF, r.y);
    }
}

// ---------------- linear: xl = x@Wl+bl, xr = x@Wr+br ----------------
template<int DIN>
__global__ __launch_bounds__(256) void k_linear(
    const float* __restrict__ x,
    const float* __restrict__ Wl, const float* __restrict__ bl,
    const float* __restrict__ Wr, const float* __restrict__ br,
    float* __restrict__ xl, float* __restrict__ xr, int n)
{
    __shared__ float sWl[DIN * 64];
    __shared__ float sWr[DIN * 64];
    __shared__ float sX[16 * DIN];
    int tid = threadIdx.x;
    for (int i = tid * 4; i < DIN * 64; i += 256 * 4) {
        *(float4*)&sWl[i] = *(const float4*)&Wl[i];
        *(float4*)&sWr[i] = *(const float4*)&Wr[i];
    }
    int nb = blockIdx.x * 16;
    int totx = n * DIN;
    for (int i = tid * 4; i < 16 * DIN; i += 256 * 4) {
        int g = nb * DIN + i;
        if (g < totx) *(float4*)&sX[i] = *(const float4*)&x[g];
    }
    __syncthreads();
    int lane = tid & 63;
    int grp = tid >> 6;          // wave id: owns nodes grp*4 .. grp*4+3
    float blv = bl[lane], brv = br[lane];
    float accL[4], accR[4];
    #pragma unroll
    for (int j = 0; j < 4; ++j) { accL[j] = blv; accR[j] = brv; }
    const float* sx0 = &sX[(grp * 4) * DIN];
    #pragma unroll 4
    for (int k = 0; k < DIN; ++k) {
        float wl = sWl[k * 64 + lane];
        float wr = sWr[k * 64 + lane];
        #pragma unroll
        for (int j = 0; j < 4; ++j) {
            float xk = sx0[j * DIN + k];    // wave-broadcast LDS read
            accL[j] += xk * wl;
            accR[j] += xk * wr;
        }
    }
    #pragma unroll
    for (int j = 0; j < 4; ++j) {
        int node = nb + grp * 4 + j;
        if (node < n) {
            xl[node * 64 + lane] = accL[j];
            xr[node * 64 + lane] = accR[j];
        }
    }
}

// ---------------- edge phase (unchanged from R13) ----------------
__global__ __launch_bounds__(256) void k_edge(
    const float* __restrict__ xl, const float* __restrict__ xr,
    const int2* __restrict__ srec,
    const int* __restrict__ offsets,
    const float* __restrict__ We, const float* __restrict__ att,
    const float* __restrict__ b,
    float* __restrict__ out, int n, int relu)
{
    int wave = threadIdx.x >> 6;
    int lane = threadIdx.x & 63;
    int v = blockIdx.x * 4 + wave;
    if (v >= n) return;
    int start = offsets[v];
    int end   = offsets[v + 1];
    float xr_c  = xr[v * 64 + lane];
    float We_c  = We[lane];
    float att_c = att[lane];
    float M = -INFINITY, S = 0.f, O = 0.f;

    for (int e = start; e < end; e += 8) {
        int cnt = end - e;                  // >= 1; pad slots i >= cnt
        int2 rec[8]; float xlc[8], p[8];
        #pragma unroll
        for (int i = 0; i < 8; ++i) {
            int ii = (i < cnt) ? i : 0;     // clamp padded loads to a valid edge
            rec[i] = srec[e + ii];
        }
        #pragma unroll
        for (int i = 0; i < 8; ++i) xlc[i] = xl[rec[i].x * 64 + lane];  // coalesced gathers
        #pragma unroll
        for (int i = 0; i < 8; ++i) {
            float m = xlc[i] + xr_c + __int_as_float(rec[i].y) * We_c;
            m = m > 0.f ? m : NEG_SLOPE * m;
            p[i] = (i < cnt) ? m * att_c : -INFINITY;   // padded -> weight 0
        }
        // multireduce: 8 vectors -> 1; lane l holds edge (l&7)'s full sum
        float q[4];
        #pragma unroll
        for (int i = 0; i < 4; ++i) {
            float a = p[2*i]   + __shfl_xor(p[2*i],   1, 64);
            float c = p[2*i+1] + __shfl_xor(p[2*i+1], 1, 64);
            q[i] = (lane & 1) ? c : a;
        }
        float r[2];
        #pragma unroll
        for (int i = 0; i < 2; ++i) {
            float a = q[2*i]   + __shfl_xor(q[2*i],   2, 64);
            float c = q[2*i+1] + __shfl_xor(q[2*i+1], 2, 64);
            r[i] = (lane & 2) ? c : a;
        }
        float s_;
        {
            float a = r[0] + __shfl_xor(r[0], 4, 64);
            float c = r[1] + __shfl_xor(r[1], 4, 64);
            s_ = (lane & 4) ? c : a;
        }
        s_ += __shfl_xor(s_, 8, 64);
        s_ += __shfl_xor(s_, 16, 64);
        s_ += __shfl_xor(s_, 32, 64);       // replicated across 8-groups

        // max over the 8 edge slots (replication makes this global)
        float bm = s_;
        bm = fmaxf(bm, __shfl_xor(bm, 1, 64));
        bm = fmaxf(bm, __shfl_xor(bm, 2, 64));
        bm = fmaxf(bm, __shfl_xor(bm, 4, 64));

        float newM = fmaxf(M, bm);
        float scale = __expf(M - newM);     // exp(-inf)=0 on first batch
        float wv = __expf(s_ - newM);       // ONE exp: this lane's edge weight

        // per-edge weights, constant-source broadcast (lanes 0..7 hold them)
        float w0 = __shfl(wv, 0, 64), w1 = __shfl(wv, 1, 64);
        float w2 = __shfl(wv, 2, 64), w3 = __shfl(wv, 3, 64);
        float w4 = __shfl(wv, 4, 64), w5 = __shfl(wv, 5, 64);
        float w6 = __shfl(wv, 6, 64), w7 = __shfl(wv, 7, 64);
        float sw = ((w0 + w1) + (w2 + w3)) + ((w4 + w5) + (w6 + w7));
        float ow = w0*xlc[0] + w1*xlc[1] + w2*xlc[2] + w3*xlc[3]
                 + w4*xlc[4] + w5*xlc[5] + w6*xlc[6] + w7*xlc[7];
        S = S * scale + sw;
        O = O * scale + ow;
        M = newM;
    }
    float res = O / (S + 1e-16f) + b[lane];
    if (relu) res = fmaxf(res, 0.f);
    out[v * 64 + lane] = res;
}

// ---------------- launcher ----------------
extern "C" void kernel_launch(void* const* d_in, const int* in_sizes, int n_in,
                              void* d_out, int out_size, void* d_ws, size_t ws_size,
                              hipStream_t stream)
{
    const float* x  = (const float*)d_in[0];
    const int*   ei = (const int*)d_in[1];
    const float* ea = (const float*)d_in[2];
    const int N = in_sizes[0] / 128;
    const int E = in_sizes[1] / 2;
    const int* src = ei;
    const int* dst = ei + E;

    const float* P[21];
    for (int i = 0; i < 21; ++i) P[i] = (const float*)d_in[3 + i];

    const int NBLK  = 256;
    const int nbuck = (N + 255) >> 8;            // 196 for N=50000
    const int chunk = (E + NBLK - 1) / NBLK;
    const int nscan = nbuck * NBLK;

    char* ws = (char*)d_ws;
    size_t off = 0;
    auto alloc = [&](size_t bytes) { char* p = ws + off; off += (bytes + 255) & ~255ULL; return p; };
    float* xl        = (float*)alloc((size_t)N * 64 * 4);
    float* xr        = (float*)alloc((size_t)N * 64 * 4);
    float* h0        = (float*)alloc((size_t)N * 64 * 4);
    float* h1        = (float*)alloc((size_t)N * 64 * 4);
    int2*  srec      = (int2*)alloc((size_t)E * 8);
    int*   blockhist = (int*)alloc((size_t)nscan * 4);
    int*   cursA     = (int*)alloc((size_t)(nscan + 1) * 4);
    int*   offsets   = (int*)alloc((size_t)(N + 1) * 4);
    int2*  tmp       = (int2*)h0;   // alias: tmp dead before layer-0 k_edge writes h0

    // ---- sort edges by dst (atomic-free two-level bucket sort) ----
    kA_hist   <<<NBLK, 256, 0, stream>>>(dst, E, nbuck, chunk, blockhist);
    k_scan    <<<1, 1024, 0, stream>>>(blockhist, nscan, cursA);
    kA_scatter<<<NBLK, 256, 0, stream>>>(src, dst, ea, E, nbuck, chunk, NBLK, cursA, tmp);
    kB_sort   <<<nbuck, 256, 0, stream>>>(tmp, cursA, NBLK, E, N, srec, offsets);

    const int lgrid = (N + 15) / 16;
    const int egrid = (N + 3) / 4;

    k_linear<128><<<lgrid, 256, 0, stream>>>(x, P[0], P[1], P[2], P[3], xl, xr, N);
    k_edge<<<egrid, 256, 0, stream>>>(xl, xr, srec, offsets, P[4], P[5], P[6], h0, N, 1);
    k_linear<64><<<lgrid, 256, 0, stream>>>(h0, P[7], P[8], P[9], P[10], xl, xr, N);
    k_edge<<<egrid, 256, 0, stream>>>(xl, xr, srec, offsets, P[11], P[12], P[13], h1, N, 1);
    k_linear<64><<<lgrid, 256, 0, stream>>>(h1, P[14], P[15], P[16], P[17], xl, xr, N);
    k_edge<<<egrid, 256, 0, stream>>>(xl, xr, srec, offsets, P[18], P[19], P[20], (float*)d_out, N, 0);
}

// Round 15
// 501.007 us; speedup vs baseline: 2.1323x; 1.0829x over previous
//
#include <hip/hip_runtime.h>
#include <math.h>

// GATv2 encoder, 3 layers, heads=1, C=64.
//   - atomic-free two-level bucket sort by dst (R13; banked: scatter off top-5)
//   - k_linear: W in LDS, k-outer register blocking
//   - k_edge (R14 rewrite): TWO nodes per wave, one per 32-lane half; lane
//     holds a channel PAIR (float2). All shuffles intra-half -> the same
//     multireduce/max/exp/broadcast instructions serve 2 nodes at once.
//     R14 counters said VALU/DS-bound (VALUBusy 77%, HBM 24%).

#define NEG_SLOPE 0.2f

// ---------------- pass A: per-(bucket,block) histogram ----------------
__global__ __launch_bounds__(256) void kA_hist(
    const int* __restrict__ dst, int E, int nbuck, int chunk,
    int* __restrict__ blockhist /* [nbuck][nblk] */)
{
    __shared__ int h[256];
    int tid = threadIdx.x, blk = blockIdx.x, nblk = gridDim.x;
    for (int i = tid; i < nbuck; i += 256) h[i] = 0;
    __syncthreads();
    int s0 = blk * chunk, s1 = min(s0 + chunk, E);
    for (int e = s0 + tid; e < s1; e += 256)
        atomicAdd(&h[dst[e] >> 8], 1);
    __syncthreads();
    for (int i = tid; i < nbuck; i += 256)
        blockhist[i * nblk + blk] = h[i];
}

// single-block exclusive scan over n counts -> offsets[n+1]
__global__ __launch_bounds__(1024) void k_scan(const int* __restrict__ counts, int n,
                                               int* __restrict__ offsets) {
    __shared__ int wsum[16];
    __shared__ int wpre[16];
    __shared__ int chunktot;
    int tid = threadIdx.x;
    int lane = tid & 63;
    int w = tid >> 6;
    int carry = 0;
    for (int base = 0; base < n; base += 1024) {
        int i = base + tid;
        int v = (i < n) ? counts[i] : 0;
        int incl = v;
        #pragma unroll
        for (int off = 1; off < 64; off <<= 1) {
            int t = __shfl_up(incl, off, 64);
            if (lane >= off) incl += t;
        }
        if (lane == 63) wsum[w] = incl;
        __syncthreads();
        if (tid == 0) {
            int acc = 0;
            #pragma unroll
            for (int j = 0; j < 16; ++j) { int t = wsum[j]; wpre[j] = acc; acc += t; }
            chunktot = acc;
        }
        __syncthreads();
        int excl = incl - v + wpre[w] + carry;
        if (i < n) offsets[i] = excl;
        carry += chunktot;
        __syncthreads();
    }
    if (tid == 0) offsets[n] = carry;
}

// ---------------- pass A scatter: edges -> bucket-grouped tmp ----------------
__global__ __launch_bounds__(256) void kA_scatter(
    const int* __restrict__ src, const int* __restrict__ dst,
    const float* __restrict__ ea, int E, int nbuck, int chunk, int nblk,
    const int* __restrict__ cursA, int2* __restrict__ tmp)
{
    __shared__ int cur[256];
    int tid = threadIdx.x, blk = blockIdx.x;
    for (int i = tid; i < nbuck; i += 256) cur[i] = cursA[i * nblk + blk];
    __syncthreads();
    int s0 = blk * chunk, s1 = min(s0 + chunk, E);
    for (int e = s0 + tid; e < s1; e += 256) {
        int d = dst[e];
        int pos = atomicAdd(&cur[d >> 8], 1);        // LDS atomic only
        tmp[pos] = make_int2((d << 16) | src[e], __float_as_int(ea[e]));
    }
}

// ---------------- pass B: within-bucket counting sort + CSR offsets ----------
__global__ __launch_bounds__(256) void kB_sort(
    const int2* __restrict__ tmp, const int* __restrict__ cursA,
    int nblk, int E, int n,
    int2* __restrict__ srec, int* __restrict__ offsets)
{
    __shared__ int h[256];
    __shared__ int cur2[256];
    int b = blockIdx.x, tid = threadIdx.x;
    int start = cursA[b * nblk];
    int end   = cursA[(b + 1) * nblk];
    h[tid] = 0;
    __syncthreads();
    for (int e = start + tid; e < end; e += 256)
        atomicAdd(&h[(tmp[e].x >> 16) & 255], 1);
    __syncthreads();
    if (tid == 0) {
        int acc = start;
        for (int i = 0; i < 256; ++i) { int c = h[i]; cur2[i] = acc; acc += c; }
    }
    __syncthreads();
    int v = (b << 8) + tid;
    if (v < n) offsets[v] = cur2[tid];
    if (b == 0 && tid == 0) offsets[n] = E;
    __syncthreads();
    for (int e = start + tid; e < end; e += 256) {
        int2 r = tmp[e];
        int pos = atomicAdd(&cur2[(r.x >> 16) & 255], 1);   // LDS atomic only
        srec[pos] = make_int2(r.x & 0xFFFF, r.y);
    }
}

// ---------------- linear: xl = x@Wl+bl, xr = x@Wr+br ----------------
template<int DIN>
__global__ __launch_bounds__(256) void k_linear(
    const float* __restrict__ x,
    const float* __restrict__ Wl, const float* __restrict__ bl,
    const float* __restrict__ Wr, const float* __restrict__ br,
    float* __restrict__ xl, float* __restrict__ xr, int n)
{
    __shared__ float sWl[DIN * 64];
    __shared__ float sWr[DIN * 64];
    __shared__ float sX[16 * DIN];
    int tid = threadIdx.x;
    for (int i = tid * 4; i < DIN * 64; i += 256 * 4) {
        *(float4*)&sWl[i] = *(const float4*)&Wl[i];
        *(float4*)&sWr[i] = *(const float4*)&Wr[i];
    }
    int nb = blockIdx.x * 16;
    int totx = n * DIN;
    for (int i = tid * 4; i < 16 * DIN; i += 256 * 4) {
        int g = nb * DIN + i;
        if (g < totx) *(float4*)&sX[i] = *(const float4*)&x[g];
    }
    __syncthreads();
    int lane = tid & 63;
    int grp = tid >> 6;          // wave id: owns nodes grp*4 .. grp*4+3
    float blv = bl[lane], brv = br[lane];
    float accL[4], accR[4];
    #pragma unroll
    for (int j = 0; j < 4; ++j) { accL[j] = blv; accR[j] = brv; }
    const float* sx0 = &sX[(grp * 4) * DIN];
    #pragma unroll 4
    for (int k = 0; k < DIN; ++k) {
        float wl = sWl[k * 64 + lane];
        float wr = sWr[k * 64 + lane];
        #pragma unroll
        for (int j = 0; j < 4; ++j) {
            float xk = sx0[j * DIN + k];    // wave-broadcast LDS read
            accL[j] += xk * wl;
            accR[j] += xk * wr;
        }
    }
    #pragma unroll
    for (int j = 0; j < 4; ++j) {
        int node = nb + grp * 4 + j;
        if (node < n) {
            xl[node * 64 + lane] = accL[j];
            xr[node * 64 + lane] = accR[j];
        }
    }
}

// ---------------- edge phase (R14: 2 nodes/wave, float2 channels) ----------
// Half h = lane>>5 owns node v = blk*8 + wave*2 + h; lane j=lane&31 holds
// channels (2j, 2j+1). All shuffles use masks <=16 or width-32 broadcasts ->
// strictly intra-half; per-half loop divergence is exec-mask safe.
__global__ __launch_bounds__(256) void k_edge(
    const float* __restrict__ xl, const float* __restrict__ xr,
    const int2* __restrict__ srec,
    const int* __restrict__ offsets,
    const float* __restrict__ We, const float* __restrict__ att,
    const float* __restrict__ b,
    float* __restrict__ out, int n, int relu)
{
    int wave = threadIdx.x >> 6;
    int lane = threadIdx.x & 63;
    int h    = lane >> 5;
    int j    = lane & 31;
    int v = blockIdx.x * 8 + wave * 2 + h;
    bool valid = v < n;
    int vv = valid ? v : n - 1;            // safe clamp; writes guarded
    int start = offsets[vv];
    int end   = valid ? offsets[vv + 1] : start;

    float2 xr_c  = *(const float2*)&xr[vv * 64 + 2 * j];
    float2 We_c  = *(const float2*)&We[2 * j];
    float2 att_c = *(const float2*)&att[2 * j];
    float2 b_c   = *(const float2*)&b[2 * j];

    float M = -INFINITY, S = 0.f;
    float Ox = 0.f, Oy = 0.f;

    for (int e = start; e < end; e += 8) {   // per-half bound (divergence OK)
        int cnt = end - e;                   // >= 1 inside loop
        int2 rec[8]; float2 xlc[8]; float p[8];
        #pragma unroll
        for (int i = 0; i < 8; ++i) {
            int ii = (i < cnt) ? i : 0;      // clamp pad to a valid edge
            rec[i] = srec[e + ii];
        }
        #pragma unroll
        for (int i = 0; i < 8; ++i)
            xlc[i] = *(const float2*)&xl[rec[i].x * 64 + 2 * j];  // 256B/half
        #pragma unroll
        for (int i = 0; i < 8; ++i) {
            float ea = __int_as_float(rec[i].y);
            float zx = xlc[i].x + xr_c.x + ea * We_c.x;
            float zy = xlc[i].y + xr_c.y + ea * We_c.y;
            zx = fmaxf(zx, NEG_SLOPE * zx);  // leaky-relu
            zy = fmaxf(zy, NEG_SLOPE * zy);
            float pp = att_c.x * zx + att_c.y * zy;   // channel-pair partial
            p[i] = (i < cnt) ? pp : -INFINITY;
        }
        // multireduce over 32 lanes: 8 vecs -> 1 (8+4+2 shuffles), then
        // xor8/xor16 complete the channel sum. Lane j holds edge (j&7).
        float q[4];
        #pragma unroll
        for (int i = 0; i < 4; ++i) {
            float a = p[2*i]   + __shfl_xor(p[2*i],   1, 64);
            float c = p[2*i+1] + __shfl_xor(p[2*i+1], 1, 64);
            q[i] = (j & 1) ? c : a;
        }
        float r[2];
        #pragma unroll
        for (int i = 0; i < 2; ++i) {
            float a = q[2*i]   + __shfl_xor(q[2*i],   2, 64);
            float c = q[2*i+1] + __shfl_xor(q[2*i+1], 2, 64);
            r[i] = (j & 2) ? c : a;
        }
        float s_;
        {
            float a = r[0] + __shfl_xor(r[0], 4, 64);
            float c = r[1] + __shfl_xor(r[1], 4, 64);
            s_ = (j & 4) ? c : a;
        }
        s_ += __shfl_xor(s_, 8, 64);
        s_ += __shfl_xor(s_, 16, 64);        // replicated across the half

        float bm = s_;
        bm = fmaxf(bm, __shfl_xor(bm, 1, 64));
        bm = fmaxf(bm, __shfl_xor(bm, 2, 64));
        bm = fmaxf(bm, __shfl_xor(bm, 4, 64));

        float newM = fmaxf(M, bm);
        float scale = __expf(M - newM);      // exp(-inf)=0 on first batch
        float wv = __expf(s_ - newM);        // lane's edge weight (edge j&7)

        // per-edge weights: width-32 broadcast (intra-half)
        float w0 = __shfl(wv, 0, 32), w1 = __shfl(wv, 1, 32);
        float w2 = __shfl(wv, 2, 32), w3 = __shfl(wv, 3, 32);
        float w4 = __shfl(wv, 4, 32), w5 = __shfl(wv, 5, 32);
        float w6 = __shfl(wv, 6, 32), w7 = __shfl(wv, 7, 32);
        float sw = ((w0 + w1) + (w2 + w3)) + ((w4 + w5) + (w6 + w7));
        float owx = w0*xlc[0].x + w1*xlc[1].x + w2*xlc[2].x + w3*xlc[3].x
                  + w4*xlc[4].x + w5*xlc[5].x + w6*xlc[6].x + w7*xlc[7].x;
        float owy = w0*xlc[0].y + w1*xlc[1].y + w2*xlc[2].y + w3*xlc[3].y
                  + w4*xlc[4].y + w5*xlc[5].y + w6*xlc[6].y + w7*xlc[7].y;
        S  = S  * scale + sw;
        Ox = Ox * scale + owx;
        Oy = Oy * scale + owy;
        M = newM;
    }
    float inv = 1.f / (S + 1e-16f);
    float rx = Ox * inv + b_c.x;
    float ry = Oy * inv + b_c.y;
    if (relu) { rx = fmaxf(rx, 0.f); ry = fmaxf(ry, 0.f); }
    if (valid) {
        float2 res = make_float2(rx, ry);
        *(float2*)&out[v * 64 + 2 * j] = res;
    }
}

// ---------------- launcher ----------------
extern "C" void kernel_launch(void* const* d_in, const int* in_sizes, int n_in,
                              void* d_out, int out_size, void* d_ws, size_t ws_size,
                              hipStream_t stream)
{
    const float* x  = (const float*)d_in[0];
    const int*   ei = (const int*)d_in[1];
    const float* ea = (const float*)d_in[2];
    const int N = in_sizes[0] / 128;
    const int E = in_sizes[1] / 2;
    const int* src = ei;
    const int* dst = ei + E;

    const float* P[21];
    for (int i = 0; i < 21; ++i) P[i] = (const float*)d_in[3 + i];

    const int NBLK  = 256;
    const int nbuck = (N + 255) >> 8;            // 196 for N=50000
    const int chunk = (E + NBLK - 1) / NBLK;
    const int nscan = nbuck * NBLK;

    char* ws = (char*)d_ws;
    size_t off = 0;
    auto alloc = [&](size_t bytes) { char* p = ws + off; off += (bytes + 255) & ~255ULL; return p; };
    float* xl        = (float*)alloc((size_t)N * 64 * 4);
    float* xr        = (float*)alloc((size_t)N * 64 * 4);
    float* h0        = (float*)alloc((size_t)N * 64 * 4);
    float* h1        = (float*)alloc((size_t)N * 64 * 4);
    int2*  srec      = (int2*)alloc((size_t)E * 8);
    int*   blockhist = (int*)alloc((size_t)nscan * 4);
    int*   cursA     = (int*)alloc((size_t)(nscan + 1) * 4);
    int*   offsets   = (int*)alloc((size_t)(N + 1) * 4);
    int2*  tmp       = (int2*)h0;   // alias: tmp dead before layer-0 k_edge writes h0

    // ---- sort edges by dst (atomic-free two-level bucket sort) ----
    kA_hist   <<<NBLK, 256, 0, stream>>>(dst, E, nbuck, chunk, blockhist);
    k_scan    <<<1, 1024, 0, stream>>>(blockhist, nscan, cursA);
    kA_scatter<<<NBLK, 256, 0, stream>>>(src, dst, ea, E, nbuck, chunk, NBLK, cursA, tmp);
    kB_sort   <<<nbuck, 256, 0, stream>>>(tmp, cursA, NBLK, E, N, srec, offsets);

    const int lgrid = (N + 15) / 16;
    const int egrid = (N + 7) / 8;               // 8 nodes per block now

    k_linear<128><<<lgrid, 256, 0, stream>>>(x, P[0], P[1], P[2], P[3], xl, xr, N);
    k_edge<<<egrid, 256, 0, stream>>>(xl, xr, srec, offsets, P[4], P[5], P[6], h0, N, 1);
    k_linear<64><<<lgrid, 256, 0, stream>>>(h0, P[7], P[8], P[9], P[10], xl, xr, N);
    k_edge<<<egrid, 256, 0, stream>>>(xl, xr, srec, offsets, P[11], P[12], P[13], h1, N, 1);
    k_linear<64><<<lgrid, 256, 0, stream>>>(h1, P[14], P[15], P[16], P[17], xl, xr, N);
    k_edge<<<egrid, 256, 0, stream>>>(xl, xr, srec, offsets, P[18], P[19], P[20], (float*)d_out, N, 0);
}

// Round 16
// 469.053 us; speedup vs baseline: 2.2775x; 1.0681x over previous
//
#include <hip/hip_runtime.h>
#include <math.h>

// GATv2 encoder, 3 layers, heads=1, C=64.
//   - atomic-free two-level bucket sort by dst (R13; banked)
//   - k_linear: W in LDS, k-outer register blocking
//   - k_edge (R16): FOUR nodes per wave, one per 16-lane quarter; lane holds
//     a channel QUAD (float4). Same multireduce/max/exp/broadcast instrs now
//     serve 4 nodes (R15 counters: VALUBusy 57%, HBM 30% -> keep amortizing
//     wave-level overhead; elementwise + gather coalescing unchanged).

#define NEG_SLOPE 0.2f

// ---------------- pass A: per-(bucket,block) histogram ----------------
__global__ __launch_bounds__(256) void kA_hist(
    const int* __restrict__ dst, int E, int nbuck, int chunk,
    int* __restrict__ blockhist /* [nbuck][nblk] */)
{
    __shared__ int h[256];
    int tid = threadIdx.x, blk = blockIdx.x, nblk = gridDim.x;
    for (int i = tid; i < nbuck; i += 256) h[i] = 0;
    __syncthreads();
    int s0 = blk * chunk, s1 = min(s0 + chunk, E);
    for (int e = s0 + tid; e < s1; e += 256)
        atomicAdd(&h[dst[e] >> 8], 1);
    __syncthreads();
    for (int i = tid; i < nbuck; i += 256)
        blockhist[i * nblk + blk] = h[i];
}

// single-block exclusive scan over n counts -> offsets[n+1]
__global__ __launch_bounds__(1024) void k_scan(const int* __restrict__ counts, int n,
                                               int* __restrict__ offsets) {
    __shared__ int wsum[16];
    __shared__ int wpre[16];
    __shared__ int chunktot;
    int tid = threadIdx.x;
    int lane = tid & 63;
    int w = tid >> 6;
    int carry = 0;
    for (int base = 0; base < n; base += 1024) {
        int i = base + tid;
        int v = (i < n) ? counts[i] : 0;
        int incl = v;
        #pragma unroll
        for (int off = 1; off < 64; off <<= 1) {
            int t = __shfl_up(incl, off, 64);
            if (lane >= off) incl += t;
        }
        if (lane == 63) wsum[w] = incl;
        __syncthreads();
        if (tid == 0) {
            int acc = 0;
            #pragma unroll
            for (int j = 0; j < 16; ++j) { int t = wsum[j]; wpre[j] = acc; acc += t; }
            chunktot = acc;
        }
        __syncthreads();
        int excl = incl - v + wpre[w] + carry;
        if (i < n) offsets[i] = excl;
        carry += chunktot;
        __syncthreads();
    }
    if (tid == 0) offsets[n] = carry;
}

// ---------------- pass A scatter: edges -> bucket-grouped tmp ----------------
__global__ __launch_bounds__(256) void kA_scatter(
    const int* __restrict__ src, const int* __restrict__ dst,
    const float* __restrict__ ea, int E, int nbuck, int chunk, int nblk,
    const int* __restrict__ cursA, int2* __restrict__ tmp)
{
    __shared__ int cur[256];
    int tid = threadIdx.x, blk = blockIdx.x;
    for (int i = tid; i < nbuck; i += 256) cur[i] = cursA[i * nblk + blk];
    __syncthreads();
    int s0 = blk * chunk, s1 = min(s0 + chunk, E);
    for (int e = s0 + tid; e < s1; e += 256) {
        int d = dst[e];
        int pos = atomicAdd(&cur[d >> 8], 1);        // LDS atomic only
        tmp[pos] = make_int2((d << 16) | src[e], __float_as_int(ea[e]));
    }
}

// ---------------- pass B: within-bucket counting sort + CSR offsets ----------
__global__ __launch_bounds__(256) void kB_sort(
    const int2* __restrict__ tmp, const int* __restrict__ cursA,
    int nblk, int E, int n,
    int2* __restrict__ srec, int* __restrict__ offsets)
{
    __shared__ int h[256];
    __shared__ int cur2[256];
    int b = blockIdx.x, tid = threadIdx.x;
    int start = cursA[b * nblk];
    int end   = cursA[(b + 1) * nblk];
    h[tid] = 0;
    __syncthreads();
    for (int e = start + tid; e < end; e += 256)
        atomicAdd(&h[(tmp[e].x >> 16) & 255], 1);
    __syncthreads();
    if (tid == 0) {
        int acc = start;
        for (int i = 0; i < 256; ++i) { int c = h[i]; cur2[i] = acc; acc += c; }
    }
    __syncthreads();
    int v = (b << 8) + tid;
    if (v < n) offsets[v] = cur2[tid];
    if (b == 0 && tid == 0) offsets[n] = E;
    __syncthreads();
    for (int e = start + tid; e < end; e += 256) {
        int2 r = tmp[e];
        int pos = atomicAdd(&cur2[(r.x >> 16) & 255], 1);   // LDS atomic only
        srec[pos] = make_int2(r.x & 0xFFFF, r.y);
    }
}

// ---------------- linear: xl = x@Wl+bl, xr = x@Wr+br ----------------
template<int DIN>
__global__ __launch_bounds__(256) void k_linear(
    const float* __restrict__ x,
    const float* __restrict__ Wl, const float* __restrict__ bl,
    const float* __restrict__ Wr, const float* __restrict__ br,
    float* __restrict__ xl, float* __restrict__ xr, int n)
{
    __shared__ float sWl[DIN * 64];
    __shared__ float sWr[DIN * 64];
    __shared__ float sX[16 * DIN];
    int tid = threadIdx.x;
    for (int i = tid * 4; i < DIN * 64; i += 256 * 4) {
        *(float4*)&sWl[i] = *(const float4*)&Wl[i];
        *(float4*)&sWr[i] = *(const float4*)&Wr[i];
    }
    int nb = blockIdx.x * 16;
    int totx = n * DIN;
    for (int i = tid * 4; i < 16 * DIN; i += 256 * 4) {
        int g = nb * DIN + i;
        if (g < totx) *(float4*)&sX[i] = *(const float4*)&x[g];
    }
    __syncthreads();
    int lane = tid & 63;
    int grp = tid >> 6;          // wave id: owns nodes grp*4 .. grp*4+3
    float blv = bl[lane], brv = br[lane];
    float accL[4], accR[4];
    #pragma unroll
    for (int j = 0; j < 4; ++j) { accL[j] = blv; accR[j] = brv; }
    const float* sx0 = &sX[(grp * 4) * DIN];
    #pragma unroll 4
    for (int k = 0; k < DIN; ++k) {
        float wl = sWl[k * 64 + lane];
        float wr = sWr[k * 64 + lane];
        #pragma unroll
        for (int j = 0; j < 4; ++j) {
            float xk = sx0[j * DIN + k];    // wave-broadcast LDS read
            accL[j] += xk * wl;
            accR[j] += xk * wr;
        }
    }
    #pragma unroll
    for (int j = 0; j < 4; ++j) {
        int node = nb + grp * 4 + j;
        if (node < n) {
            xl[node * 64 + lane] = accL[j];
            xr[node * 64 + lane] = accR[j];
        }
    }
}

// ---------------- edge phase (R16: 4 nodes/wave, float4 channels) ----------
// Quarter q = lane>>4 owns node v = blk*16 + wave*4 + q; lane j=lane&15
// holds channels 4j..4j+3. All shuffles use masks <=8 or width-16 broadcasts
// -> strictly intra-quarter; per-quarter loop divergence is exec-mask safe.
__global__ __launch_bounds__(256) void k_edge(
    const float* __restrict__ xl, const float* __restrict__ xr,
    const int2* __restrict__ srec,
    const int* __restrict__ offsets,
    const float* __restrict__ We, const float* __restrict__ att,
    const float* __restrict__ b,
    float* __restrict__ out, int n, int relu)
{
    int wave = threadIdx.x >> 6;
    int lane = threadIdx.x & 63;
    int qt   = lane >> 4;          // quarter 0..3
    int j    = lane & 15;          // channels 4j..4j+3
    int v = blockIdx.x * 16 + wave * 4 + qt;
    bool valid = v < n;
    int vv = valid ? v : n - 1;            // safe clamp; writes guarded
    int start = offsets[vv];
    int end   = valid ? offsets[vv + 1] : start;

    float4 xr_c  = *(const float4*)&xr[vv * 64 + 4 * j];
    float4 We_c  = *(const float4*)&We[4 * j];
    float4 att_c = *(const float4*)&att[4 * j];
    float4 b_c   = *(const float4*)&b[4 * j];

    float M = -INFINITY, S = 0.f;
    float Ox = 0.f, Oy = 0.f, Oz = 0.f, Ow = 0.f;

    for (int e = start; e < end; e += 8) {   // per-quarter bound
        int cnt = end - e;                   // >= 1 inside loop
        int2 rec[8]; float4 xlc[8]; float p[8];
        #pragma unroll
        for (int i = 0; i < 8; ++i) {
            int ii = (i < cnt) ? i : 0;      // clamp pad to a valid edge
            rec[i] = srec[e + ii];
        }
        #pragma unroll
        for (int i = 0; i < 8; ++i)
            xlc[i] = *(const float4*)&xl[rec[i].x * 64 + 4 * j];  // 256B/quarter
        #pragma unroll
        for (int i = 0; i < 8; ++i) {
            float ea = __int_as_float(rec[i].y);
            float zx = xlc[i].x + xr_c.x + ea * We_c.x;
            float zy = xlc[i].y + xr_c.y + ea * We_c.y;
            float zz = xlc[i].z + xr_c.z + ea * We_c.z;
            float zw = xlc[i].w + xr_c.w + ea * We_c.w;
            zx = fmaxf(zx, NEG_SLOPE * zx);  // leaky-relu
            zy = fmaxf(zy, NEG_SLOPE * zy);
            zz = fmaxf(zz, NEG_SLOPE * zz);
            zw = fmaxf(zw, NEG_SLOPE * zw);
            float pp = att_c.x * zx + att_c.y * zy + att_c.z * zz + att_c.w * zw;
            p[i] = (i < cnt) ? pp : -INFINITY;
        }
        // multireduce over 16 lanes: 8 vecs -> 1 (8+4+2 shuffles), xor8
        // completes the channel sum. Lane j then holds edge (j&7)'s logit.
        float qq[4];
        #pragma unroll
        for (int i = 0; i < 4; ++i) {
            float a = p[2*i]   + __shfl_xor(p[2*i],   1, 64);
            float c = p[2*i+1] + __shfl_xor(p[2*i+1], 1, 64);
            qq[i] = (j & 1) ? c : a;
        }
        float rr[2];
        #pragma unroll
        for (int i = 0; i < 2; ++i) {
            float a = qq[2*i]   + __shfl_xor(qq[2*i],   2, 64);
            float c = qq[2*i+1] + __shfl_xor(qq[2*i+1], 2, 64);
            rr[i] = (j & 2) ? c : a;
        }
        float s_;
        {
            float a = rr[0] + __shfl_xor(rr[0], 4, 64);
            float c = rr[1] + __shfl_xor(rr[1], 4, 64);
            s_ = (j & 4) ? c : a;
        }
        s_ += __shfl_xor(s_, 8, 64);         // replicated across the quarter

        float bm = s_;
        bm = fmaxf(bm, __shfl_xor(bm, 1, 64));
        bm = fmaxf(bm, __shfl_xor(bm, 2, 64));
        bm = fmaxf(bm, __shfl_xor(bm, 4, 64));

        float newM = fmaxf(M, bm);
        float scale = __expf(M - newM);      // exp(-inf)=0 on first batch
        float wv = __expf(s_ - newM);        // lane's edge weight (edge j&7)

        // per-edge weights: width-16 broadcast (intra-quarter)
        float w0 = __shfl(wv, 0, 16), w1 = __shfl(wv, 1, 16);
        float w2 = __shfl(wv, 2, 16), w3 = __shfl(wv, 3, 16);
        float w4 = __shfl(wv, 4, 16), w5 = __shfl(wv, 5, 16);
        float w6 = __shfl(wv, 6, 16), w7 = __shfl(wv, 7, 16);
        float sw = ((w0 + w1) + (w2 + w3)) + ((w4 + w5) + (w6 + w7));
        float owx = w0*xlc[0].x + w1*xlc[1].x + w2*xlc[2].x + w3*xlc[3].x
                  + w4*xlc[4].x + w5*xlc[5].x + w6*xlc[6].x + w7*xlc[7].x;
        float owy = w0*xlc[0].y + w1*xlc[1].y + w2*xlc[2].y + w3*xlc[3].y
                  + w4*xlc[4].y + w5*xlc[5].y + w6*xlc[6].y + w7*xlc[7].y;
        float owz = w0*xlc[0].z + w1*xlc[1].z + w2*xlc[2].z + w3*xlc[3].z
                  + w4*xlc[4].z + w5*xlc[5].z + w6*xlc[6].z + w7*xlc[7].z;
        float oww = w0*xlc[0].w + w1*xlc[1].w + w2*xlc[2].w + w3*xlc[3].w
                  + w4*xlc[4].w + w5*xlc[5].w + w6*xlc[6].w + w7*xlc[7].w;
        S  = S  * scale + sw;
        Ox = Ox * scale + owx;
        Oy = Oy * scale + owy;
        Oz = Oz * scale + owz;
        Ow = Ow * scale + oww;
        M = newM;
    }
    float inv = 1.f / (S + 1e-16f);
    float rx = Ox * inv + b_c.x;
    float ry = Oy * inv + b_c.y;
    float rz = Oz * inv + b_c.z;
    float rw = Ow * inv + b_c.w;
    if (relu) {
        rx = fmaxf(rx, 0.f); ry = fmaxf(ry, 0.f);
        rz = fmaxf(rz, 0.f); rw = fmaxf(rw, 0.f);
    }
    if (valid) {
        float4 res = make_float4(rx, ry, rz, rw);
        *(float4*)&out[v * 64 + 4 * j] = res;
    }
}

// ---------------- launcher ----------------
extern "C" void kernel_launch(void* const* d_in, const int* in_sizes, int n_in,
                              void* d_out, int out_size, void* d_ws, size_t ws_size,
                              hipStream_t stream)
{
    const float* x  = (const float*)d_in[0];
    const int*   ei = (const int*)d_in[1];
    const float* ea = (const float*)d_in[2];
    const int N = in_sizes[0] / 128;
    const int E = in_sizes[1] / 2;
    const int* src = ei;
    const int* dst = ei + E;

    const float* P[21];
    for (int i = 0; i < 21; ++i) P[i] = (const float*)d_in[3 + i];

    const int NBLK  = 256;
    const int nbuck = (N + 255) >> 8;            // 196 for N=50000
    const int chunk = (E + NBLK - 1) / NBLK;
    const int nscan = nbuck * NBLK;

    char* ws = (char*)d_ws;
    size_t off = 0;
    auto alloc = [&](size_t bytes) { char* p = ws + off; off += (bytes + 255) & ~255ULL; return p; };
    float* xl        = (float*)alloc((size_t)N * 64 * 4);
    float* xr        = (float*)alloc((size_t)N * 64 * 4);
    float* h0        = (float*)alloc((size_t)N * 64 * 4);
    float* h1        = (float*)alloc((size_t)N * 64 * 4);
    int2*  srec      = (int2*)alloc((size_t)E * 8);
    int*   blockhist = (int*)alloc((size_t)nscan * 4);
    int*   cursA     = (int*)alloc((size_t)(nscan + 1) * 4);
    int*   offsets   = (int*)alloc((size_t)(N + 1) * 4);
    int2*  tmp       = (int2*)h0;   // alias: tmp dead before layer-0 k_edge writes h0

    // ---- sort edges by dst (atomic-free two-level bucket sort) ----
    kA_hist   <<<NBLK, 256, 0, stream>>>(dst, E, nbuck, chunk, blockhist);
    k_scan    <<<1, 1024, 0, stream>>>(blockhist, nscan, cursA);
    kA_scatter<<<NBLK, 256, 0, stream>>>(src, dst, ea, E, nbuck, chunk, NBLK, cursA, tmp);
    kB_sort   <<<nbuck, 256, 0, stream>>>(tmp, cursA, NBLK, E, N, srec, offsets);

    const int lgrid = (N + 15) / 16;
    const int egrid = (N + 15) / 16;             // 16 nodes per block now

    k_linear<128><<<lgrid, 256, 0, stream>>>(x, P[0], P[1], P[2], P[3], xl, xr, N);
    k_edge<<<egrid, 256, 0, stream>>>(xl, xr, srec, offsets, P[4], P[5], P[6], h0, N, 1);
    k_linear<64><<<lgrid, 256, 0, stream>>>(h0, P[7], P[8], P[9], P[10], xl, xr, N);
    k_edge<<<egrid, 256, 0, stream>>>(xl, xr, srec, offsets, P[11], P[12], P[13], h1, N, 1);
    k_linear<64><<<lgrid, 256, 0, stream>>>(h1, P[14], P[15], P[16], P[17], xl, xr, N);
    k_edge<<<egrid, 256, 0, stream>>>(xl, xr, srec, offsets, P[18], P[19], P[20], (float*)d_out, N, 0);
}